// Round 1
// baseline (563.265 us; speedup 1.0000x reference)
//
#include <hip/hip_runtime.h>

// MHA forward: x[4096,1024] fp32, W{q,k,v,o}[1024,1024] fp32 -> out[4096,1024] fp32
// Pipeline: cvt->bf16 | QKV gemms (bf16 MFMA) | RoPE+relayout | flash attn | O-proj gemm

typedef __attribute__((ext_vector_type(4))) float f32x4;
typedef __attribute__((ext_vector_type(8))) short short8;
typedef unsigned short u16;

#define SEQ 4096
#define DIMM 1024
#define NH 16
#define HD 64

__device__ __forceinline__ u16 f2b(float f) {
  unsigned u = __float_as_uint(f);
  u += 0x7FFFu + ((u >> 16) & 1u);
  return (u16)(u >> 16);
}

__device__ __forceinline__ f32x4 mfma16(short8 a, short8 b, f32x4 c) {
  return __builtin_amdgcn_mfma_f32_16x16x32_bf16(a, b, c, 0, 0, 0);
}

// ---------------- convert x + 4 weights to bf16 (vectorized float4 -> 4xbf16) ----
__global__ __launch_bounds__(256) void cvt_all(
    const float* __restrict__ x, const float* __restrict__ wq,
    const float* __restrict__ wk, const float* __restrict__ wv,
    const float* __restrict__ wo,
    u16* __restrict__ xb, u16* __restrict__ wqb, u16* __restrict__ wkb,
    u16* __restrict__ wvb, u16* __restrict__ wob) {
  int i = blockIdx.x * 256 + threadIdx.x;  // 0 .. 2097152-1 (float4 units)
  const float* src;
  u16* dst;
  int j;
  if (i < 1048576) {            // x: 4194304 elems / 4
    src = x; dst = xb; j = i;
  } else {
    int t = i - 1048576;
    int wsel = t >> 18;         // 262144 float4 per weight
    j = t & 262143;
    src = (wsel == 0) ? wq : (wsel == 1) ? wk : (wsel == 2) ? wv : wo;
    dst = (wsel == 0) ? wqb : (wsel == 1) ? wkb : (wsel == 2) ? wvb : wob;
  }
  float4 v = ((const float4*)src)[j];
  ushort4 o;
  o.x = f2b(v.x); o.y = f2b(v.y); o.z = f2b(v.z); o.w = f2b(v.w);
  ((ushort4*)dst)[j] = o;
}

// ---------------- GEMM: C[M,N] = A[M,K] * B[N,K]^T  (bf16 in, fp32 out) ---------
// 128x128 tile, BK=32, 256 threads = 4 waves (2x2), wave does 64x64 via 4x4 MFMA frags
__global__ __launch_bounds__(256) void gemm_bt(
    const u16* __restrict__ A, const u16* __restrict__ B, float* __restrict__ C,
    int K, int N) {
  __shared__ u16 As[128 * 40];   // stride 40 elems (80B) -> 2-way banks only
  __shared__ u16 Bs[128 * 40];
  const int tid = threadIdx.x;
  const int bm = blockIdx.x, bn = blockIdx.y;
  const int w = tid >> 6, lane = tid & 63;
  const int wm = w >> 1, wn = w & 1;
  const int l15 = lane & 15, g = lane >> 4;

  f32x4 acc[4][4] = {};

  const int e0 = tid * 8;
  const int r0 = e0 >> 5, c0 = e0 & 31;
  const int e1 = (tid + 256) * 8;
  const int r1 = e1 >> 5, c1 = e1 & 31;
  const u16* Ar0 = A + (size_t)(bm * 128 + r0) * K + c0;
  const u16* Ar1 = A + (size_t)(bm * 128 + r1) * K + c1;
  const u16* Br0 = B + (size_t)(bn * 128 + r0) * K + c0;
  const u16* Br1 = B + (size_t)(bn * 128 + r1) * K + c1;

  for (int k0 = 0; k0 < K; k0 += 32) {
    short8 a0 = *(const short8*)(Ar0 + k0);
    short8 a1 = *(const short8*)(Ar1 + k0);
    short8 b0 = *(const short8*)(Br0 + k0);
    short8 b1 = *(const short8*)(Br1 + k0);
    __syncthreads();
    *(short8*)&As[r0 * 40 + c0] = a0;
    *(short8*)&As[r1 * 40 + c1] = a1;
    *(short8*)&Bs[r0 * 40 + c0] = b0;
    *(short8*)&Bs[r1 * 40 + c1] = b1;
    __syncthreads();
    short8 af[4], bf[4];
#pragma unroll
    for (int m = 0; m < 4; ++m)
      af[m] = *(const short8*)&As[(wm * 64 + m * 16 + l15) * 40 + g * 8];
#pragma unroll
    for (int n = 0; n < 4; ++n)
      bf[n] = *(const short8*)&Bs[(wn * 64 + n * 16 + l15) * 40 + g * 8];
#pragma unroll
    for (int m = 0; m < 4; ++m)
#pragma unroll
      for (int n = 0; n < 4; ++n)
        acc[m][n] = mfma16(af[m], bf[n], acc[m][n]);
  }

#pragma unroll
  for (int m = 0; m < 4; ++m) {
    int grow = bm * 128 + wm * 64 + m * 16 + g * 4;
#pragma unroll
    for (int n = 0; n < 4; ++n) {
      int gcol = bn * 128 + wn * 64 + n * 16 + l15;
#pragma unroll
      for (int r = 0; r < 4; ++r)
        C[(size_t)(grow + r) * N + gcol] = acc[m][n][r];
    }
  }
}

// ---------------- RoPE + head-major bf16 relayout -------------------------------
// q,k,v fp32 [4096][1024] -> Qh/Kh/Vh bf16 [16][4096][64]; Q scaled by 1/8
__global__ __launch_bounds__(256) void rope_cvt(
    const float* __restrict__ q, const float* __restrict__ k,
    const float* __restrict__ v, u16* __restrict__ Qh, u16* __restrict__ Kh,
    u16* __restrict__ Vh) {
  int gid = blockIdx.x * 256 + threadIdx.x;  // 4096*32
  int s = gid >> 5, i = gid & 31;
  float inv = powf(10000.0f, -(float)i * (1.0f / 32.0f));
  float ang = (float)s * inv;
  float sv, cv;
  sincosf(ang, &sv, &cv);
#pragma unroll
  for (int h = 0; h < NH; ++h) {
    size_t base = (size_t)s * DIMM + h * HD + 2 * i;
    float2 qv = *(const float2*)(q + base);
    float2 kv = *(const float2*)(k + base);
    float2 vv = *(const float2*)(v + base);
    size_t ob = ((size_t)h * SEQ + s) * HD + 2 * i;
    ushort2 t;
    t.x = f2b((qv.x * cv - qv.y * sv) * 0.125f);
    t.y = f2b((qv.y * cv + qv.x * sv) * 0.125f);
    *(ushort2*)(Qh + ob) = t;
    t.x = f2b(kv.x * cv - kv.y * sv);
    t.y = f2b(kv.y * cv + kv.x * sv);
    *(ushort2*)(Kh + ob) = t;
    t.x = f2b(vv.x);
    t.y = f2b(vv.y);
    *(ushort2*)(Vh + ob) = t;
  }
}

// ---------------- causal flash attention ----------------------------------------
// grid (64 qblocks, 16 heads), 256 thr = 4 waves; wave w owns q rows qb*64+w*16..+15
__global__ __launch_bounds__(256) void attn_fwd(
    const u16* __restrict__ Qh, const u16* __restrict__ Kh,
    const u16* __restrict__ Vh, u16* __restrict__ Ob) {
  __shared__ u16 Ks[32 * 72];      // K tile [32 kv][64 d], stride 72
  __shared__ u16 Vt[64 * 40];      // V^T tile [64 d][32 kv], stride 40
  __shared__ u16 Ps[4][16 * 40];   // per-wave P [16 q][32 kv], stride 40

  const int qb = blockIdx.x, h = blockIdx.y;
  const int tid = threadIdx.x, w = tid >> 6, lane = tid & 63;
  const int l15 = lane & 15, g = lane >> 4;
  const int qr0 = qb * 64 + w * 16;
  const int koff = g * 8;

  const u16* Qp = Qh + ((size_t)h * SEQ + qr0 + l15) * HD + koff;
  short8 qf0 = *(const short8*)(Qp);
  short8 qf1 = *(const short8*)(Qp + 32);

  f32x4 o[4] = {};
  float m_[4] = {-3.0e38f, -3.0e38f, -3.0e38f, -3.0e38f};
  float l_[4] = {0.f, 0.f, 0.f, 0.f};

  const int ntiles = 2 * qb + 2;
  for (int t = 0; t < ntiles; ++t) {
    const int kv0 = t * 32;
    __syncthreads();
    {  // stage K tile (all 256 threads)
      int r = tid >> 3, c = (tid & 7) * 8;
      *(short8*)&Ks[r * 72 + c] =
          *(const short8*)(Kh + ((size_t)h * SEQ + kv0 + r) * HD + c);
    }
    if (tid < 128) {  // stage V transposed, pair-packed
      int kvp = tid >> 3, d0 = (tid & 7) * 8;
      const u16* vp = Vh + ((size_t)h * SEQ + kv0 + kvp * 2) * HD + d0;
      short8 va = *(const short8*)vp;
      short8 vb = *(const short8*)(vp + HD);
#pragma unroll
      for (int j = 0; j < 8; ++j) {
        ushort2 pr;
        pr.x = (u16)va[j];
        pr.y = (u16)vb[j];
        *(ushort2*)&Vt[(d0 + j) * 40 + kvp * 2] = pr;
      }
    }
    __syncthreads();
    if (kv0 > qr0 + 15) continue;  // wave entirely above diagonal

    // ---- QK^T: S[16 q x 32 kv]
    f32x4 s0 = {0.f, 0.f, 0.f, 0.f}, s1 = {0.f, 0.f, 0.f, 0.f};
    {
      short8 kf;
      kf = *(const short8*)&Ks[l15 * 72 + koff];
      s0 = mfma16(qf0, kf, s0);
      kf = *(const short8*)&Ks[l15 * 72 + 32 + koff];
      s0 = mfma16(qf1, kf, s0);
      kf = *(const short8*)&Ks[(16 + l15) * 72 + koff];
      s1 = mfma16(qf0, kf, s1);
      kf = *(const short8*)&Ks[(16 + l15) * 72 + 32 + koff];
      s1 = mfma16(qf1, kf, s1);
    }
    if (kv0 + 31 > qr0) {  // diagonal tile: causal mask
#pragma unroll
      for (int r = 0; r < 4; ++r) {
        int qr = qr0 + g * 4 + r;
        if (kv0 + l15 > qr) s0[r] = -1.0e30f;
        if (kv0 + 16 + l15 > qr) s1[r] = -1.0e30f;
      }
    }
    // ---- online softmax (rows spread over 16-lane groups)
#pragma unroll
    for (int r = 0; r < 4; ++r) {
      float mx = fmaxf(s0[r], s1[r]);
      mx = fmaxf(mx, __shfl_xor(mx, 1));
      mx = fmaxf(mx, __shfl_xor(mx, 2));
      mx = fmaxf(mx, __shfl_xor(mx, 4));
      mx = fmaxf(mx, __shfl_xor(mx, 8));
      float nm = fmaxf(m_[r], mx);
      float scale = __expf(m_[r] - nm);
      float p0 = __expf(s0[r] - nm);
      float p1 = __expf(s1[r] - nm);
      float rs = p0 + p1;
      rs += __shfl_xor(rs, 1);
      rs += __shfl_xor(rs, 2);
      rs += __shfl_xor(rs, 4);
      rs += __shfl_xor(rs, 8);
      l_[r] = l_[r] * scale + rs;
      m_[r] = nm;
      o[0][r] *= scale;
      o[1][r] *= scale;
      o[2][r] *= scale;
      o[3][r] *= scale;
      u16* pw = &Ps[w][(g * 4 + r) * 40];
      pw[l15] = f2b(p0);
      pw[16 + l15] = f2b(p1);
    }
    // ---- PV: O += P[16x32] * V[32x64]
    short8 pf = *(const short8*)&Ps[w][l15 * 40 + koff];
#pragma unroll
    for (int nb = 0; nb < 4; ++nb) {
      short8 vf = *(const short8*)&Vt[(nb * 16 + l15) * 40 + koff];
      o[nb] = mfma16(pf, vf, o[nb]);
    }
  }

  // epilogue: normalize, write interleaved [s][h*64+d] bf16
  float invl[4];
#pragma unroll
  for (int r = 0; r < 4; ++r) invl[r] = 1.0f / l_[r];
#pragma unroll
  for (int nb = 0; nb < 4; ++nb) {
#pragma unroll
    for (int r = 0; r < 4; ++r) {
      int row = qr0 + g * 4 + r;
      int col = h * HD + nb * 16 + l15;
      Ob[(size_t)row * DIMM + col] = f2b(o[nb][r] * invl[r]);
    }
  }
}

// ---------------- workspace layout (bytes) --------------------------------------
#define OFF_XB 0u
#define OFF_WQB 8388608u
#define OFF_WKB 10485760u
#define OFF_WVB 12582912u
#define OFF_WOB 14680064u
#define OFF_QKV 16777216u   // fp32 q,k,v each 16777216 B
#define OFF_QH 67108864u
#define OFF_KH 75497472u
#define OFF_VH 83886080u
#define OFF_OB 92274688u
// end: 100663296 (96 MB)

extern "C" void kernel_launch(void* const* d_in, const int* in_sizes, int n_in,
                              void* d_out, int out_size, void* d_ws, size_t ws_size,
                              hipStream_t stream) {
  const float* x = (const float*)d_in[0];
  const float* Wq = (const float*)d_in[1];
  const float* Wk = (const float*)d_in[2];
  const float* Wv = (const float*)d_in[3];
  const float* Wo = (const float*)d_in[4];
  float* out = (float*)d_out;
  char* ws = (char*)d_ws;

  u16* xb = (u16*)(ws + OFF_XB);
  u16* wqb = (u16*)(ws + OFF_WQB);
  u16* wkb = (u16*)(ws + OFF_WKB);
  u16* wvb = (u16*)(ws + OFF_WVB);
  u16* wob = (u16*)(ws + OFF_WOB);
  float* qf = (float*)(ws + OFF_QKV);
  float* kf = qf + (size_t)SEQ * DIMM;
  float* vf = kf + (size_t)SEQ * DIMM;
  u16* Qh = (u16*)(ws + OFF_QH);
  u16* Kh = (u16*)(ws + OFF_KH);
  u16* Vh = (u16*)(ws + OFF_VH);
  u16* Ob = (u16*)(ws + OFF_OB);

  cvt_all<<<8192, 256, 0, stream>>>(x, Wq, Wk, Wv, Wo, xb, wqb, wkb, wvb, wob);

  dim3 gg(SEQ / 128, DIMM / 128);
  gemm_bt<<<gg, 256, 0, stream>>>(xb, wqb, qf, DIMM, DIMM);
  gemm_bt<<<gg, 256, 0, stream>>>(xb, wkb, kf, DIMM, DIMM);
  gemm_bt<<<gg, 256, 0, stream>>>(xb, wvb, vf, DIMM, DIMM);

  rope_cvt<<<(SEQ * 32) / 256, 256, 0, stream>>>(qf, kf, vf, Qh, Kh, Vh);

  attn_fwd<<<dim3(SEQ / 64, NH), 256, 0, stream>>>(Qh, Kh, Vh, Ob);

  gemm_bt<<<gg, 256, 0, stream>>>(Ob, wob, out, DIMM, DIMM);
}

// Round 2
// 321.090 us; speedup vs baseline: 1.7542x; 1.7542x over previous
//
#include <hip/hip_runtime.h>

// MHA forward: x[4096,1024] fp32, W{q,k,v,o}[1024,1024] fp32 -> out[4096,1024] fp32
// Pipeline: cvt->bf16 | fused QKV gemm (m97-style MFMA) | RoPE+relayout | flash attn
//           (KVBLK=64, XOR-swizzled LDS, causal-pair balanced) | O-proj gemm

typedef __attribute__((ext_vector_type(4))) float f32x4;
typedef __attribute__((ext_vector_type(8))) short short8;
typedef unsigned short u16;

#define SEQ 4096
#define DIMM 1024
#define NH 16
#define HD 64

__device__ __forceinline__ u16 f2b(float f) {
  unsigned u = __float_as_uint(f);
  u += 0x7FFFu + ((u >> 16) & 1u);
  return (u16)(u >> 16);
}

__device__ __forceinline__ f32x4 mfma16(short8 a, short8 b, f32x4 c) {
  return __builtin_amdgcn_mfma_f32_16x16x32_bf16(a, b, c, 0, 0, 0);
}

// global -> LDS direct DMA, 16B per lane; dest = wave-uniform base + lane*16
#define GLL16(gp, lp)                                                        \
  __builtin_amdgcn_global_load_lds(                                          \
      (const __attribute__((address_space(1))) unsigned int*)(gp),           \
      (__attribute__((address_space(3))) unsigned int*)(lp), 16, 0, 0)

// ---------------- convert x + 4 weights to bf16 ---------------------------------
__global__ __launch_bounds__(256) void cvt_all(
    const float* __restrict__ x, const float* __restrict__ wq,
    const float* __restrict__ wk, const float* __restrict__ wv,
    const float* __restrict__ wo,
    u16* __restrict__ xb, u16* __restrict__ wqb, u16* __restrict__ wkb,
    u16* __restrict__ wvb, u16* __restrict__ wob) {
  int i = blockIdx.x * 256 + threadIdx.x;  // float4 units
  const float* src;
  u16* dst;
  int j;
  if (i < 1048576) {
    src = x; dst = xb; j = i;
  } else {
    int t = i - 1048576;
    int wsel = t >> 18;
    j = t & 262143;
    src = (wsel == 0) ? wq : (wsel == 1) ? wk : (wsel == 2) ? wv : wo;
    dst = (wsel == 0) ? wqb : (wsel == 1) ? wkb : (wsel == 2) ? wvb : wob;
  }
  float4 v = ((const float4*)src)[j];
  ushort4 o;
  o.x = f2b(v.x); o.y = f2b(v.y); o.z = f2b(v.z); o.w = f2b(v.w);
  ((ushort4*)dst)[j] = o;
}

// ---------------- GEMM: C[M,N] = A[M,K] * B[N,K]^T  (bf16 in, fp32 out) ---------
// m97 structure: 128x128 tile, BK=32, global_load_lds w=16, linear LDS [128][32]
__global__ __launch_bounds__(256) void gemm_bt(
    const u16* __restrict__ A, const u16* __restrict__ B, float* __restrict__ C,
    int K, int N) {
  __shared__ __align__(16) u16 As[128 * 32];
  __shared__ __align__(16) u16 Bs[128 * 32];
  const int tid = threadIdx.x;
  const int bm = blockIdx.x, bn = blockIdx.y;
  const int w = tid >> 6, lane = tid & 63;
  const int wm = w >> 1, wn = w & 1;
  const int l15 = lane & 15, g = lane >> 4;

  f32x4 acc[4][4] = {};

  // staging: 512 16B-chunks per tile; chunk ci = call*256 + tid; row=ci>>2 col=(ci&3)*8
  const u16* Ap0 = A + (size_t)(bm * 128 + (tid >> 2)) * K + (tid & 3) * 8;
  const u16* Ap1 = Ap0 + (size_t)64 * K;
  const u16* Bp0 = B + (size_t)(bn * 128 + (tid >> 2)) * K + (tid & 3) * 8;
  const u16* Bp1 = Bp0 + (size_t)64 * K;
  u16* ldsA0 = &As[w * 512];
  u16* ldsA1 = &As[2048 + w * 512];
  u16* ldsB0 = &Bs[w * 512];
  u16* ldsB1 = &Bs[2048 + w * 512];

  for (int k0 = 0; k0 < K; k0 += 32) {
    __syncthreads();
    GLL16(Ap0 + k0, ldsA0);
    GLL16(Ap1 + k0, ldsA1);
    GLL16(Bp0 + k0, ldsB0);
    GLL16(Bp1 + k0, ldsB1);
    __syncthreads();
    short8 af[4], bf[4];
#pragma unroll
    for (int m = 0; m < 4; ++m)
      af[m] = *(const short8*)&As[(wm * 64 + m * 16 + l15) * 32 + g * 8];
#pragma unroll
    for (int n = 0; n < 4; ++n)
      bf[n] = *(const short8*)&Bs[(wn * 64 + n * 16 + l15) * 32 + g * 8];
#pragma unroll
    for (int m = 0; m < 4; ++m)
#pragma unroll
      for (int n = 0; n < 4; ++n)
        acc[m][n] = mfma16(af[m], bf[n], acc[m][n]);
  }

#pragma unroll
  for (int m = 0; m < 4; ++m) {
    int grow = bm * 128 + wm * 64 + m * 16 + g * 4;
#pragma unroll
    for (int n = 0; n < 4; ++n) {
      int gcol = bn * 128 + wn * 64 + n * 16 + l15;
#pragma unroll
      for (int r = 0; r < 4; ++r)
        C[(size_t)(grow + r) * N + gcol] = acc[m][n][r];
    }
  }
}

// ---------------- RoPE + head-major bf16 relayout -------------------------------
// qkv fp32 [4096][3072] -> Qh/Kh/Vh bf16 [16][4096][64]; Q scaled by 1/8
__global__ __launch_bounds__(256) void rope_cvt(
    const float* __restrict__ qkv, u16* __restrict__ Qh, u16* __restrict__ Kh,
    u16* __restrict__ Vh) {
  int gid = blockIdx.x * 256 + threadIdx.x;  // 4096*32
  int s = gid >> 5, i = gid & 31;
  float inv = powf(10000.0f, -(float)i * (1.0f / 32.0f));
  float ang = (float)s * inv;
  float sv, cv;
  sincosf(ang, &sv, &cv);
#pragma unroll
  for (int h = 0; h < NH; ++h) {
    size_t base = (size_t)s * 3072 + h * HD + 2 * i;
    float2 qv = *(const float2*)(qkv + base);
    float2 kv = *(const float2*)(qkv + base + 1024);
    float2 vv = *(const float2*)(qkv + base + 2048);
    size_t ob = ((size_t)h * SEQ + s) * HD + 2 * i;
    ushort2 t;
    t.x = f2b((qv.x * cv - qv.y * sv) * 0.125f);
    t.y = f2b((qv.y * cv + qv.x * sv) * 0.125f);
    *(ushort2*)(Qh + ob) = t;
    t.x = f2b(kv.x * cv - kv.y * sv);
    t.y = f2b(kv.y * cv + kv.x * sv);
    *(ushort2*)(Kh + ob) = t;
    t.x = f2b(vv.x);
    t.y = f2b(vv.y);
    *(ushort2*)(Vh + ob) = t;
  }
}

// ---------------- causal flash attention ----------------------------------------
// grid (32, 16); block = 4 waves; wave owns 16 q rows; KVBLK=64.
// Block bx processes q-chunks bx and 63-bx (65 KV-tiles total -> perfectly balanced).
// All [*][64]-u16 LDS tiles XOR-swizzled: 16B-chunk' = chunk ^ (row&7).
__global__ __launch_bounds__(256) void attn_fwd(
    const u16* __restrict__ Qh, const u16* __restrict__ Kh,
    const u16* __restrict__ Vh, u16* __restrict__ Ob) {
  __shared__ __align__(16) u16 Ks[64 * 64];     // [kv][d] swizzled
  __shared__ __align__(16) u16 Vt[64 * 64];     // [d][kv] swizzled
  __shared__ __align__(16) u16 Ps[4][16 * 64];  // per-wave [q][kv] swizzled

  const int bx = blockIdx.x, h = blockIdx.y;
  const int tid = threadIdx.x, w = tid >> 6, lane = tid & 63;
  const int l15 = lane & 15, g = lane >> 4;

  // staging geometry (same every tile)
  const int krow0 = w * 8 + (lane >> 3);        // K gll call0 row (0..31)
  const int kc0 = ((lane & 7) ^ (krow0 & 7)) * 8;
  const int krow1 = 32 + krow0;                 // call1 row (32..63)
  const int kc1 = ((lane & 7) ^ (krow1 & 7)) * 8;
  const int kvp = tid >> 3, d0 = (tid & 7) * 8; // V transpose staging

  for (int cc = 0; cc < 2; ++cc) {
    const int c = cc ? (63 - bx) : bx;
    const int qr0 = c * 64 + w * 16;
    const u16* Qp = Qh + ((size_t)h * SEQ + qr0 + l15) * HD + g * 8;
    short8 qf0 = *(const short8*)(Qp);
    short8 qf1 = *(const short8*)(Qp + 32);

    f32x4 o[4] = {};
    float m_[4] = {-3.0e38f, -3.0e38f, -3.0e38f, -3.0e38f};
    float l_[4] = {0.f, 0.f, 0.f, 0.f};

    for (int t = 0; t <= c; ++t) {
      const int kv0 = t * 64;
      __syncthreads();
      // --- K tile via global_load_lds, source pre-swizzled
      GLL16(Kh + ((size_t)h * SEQ + kv0 + krow0) * HD + kc0, &Ks[w * 512]);
      GLL16(Kh + ((size_t)h * SEQ + kv0 + krow1) * HD + kc1, &Ks[2048 + w * 512]);
      // --- V tile transposed (reg-staged), swizzled writes
      {
        const u16* vp = Vh + ((size_t)h * SEQ + kv0 + kvp * 2) * HD + d0;
        short8 va = *(const short8*)vp;
        short8 vb = *(const short8*)(vp + HD);
#pragma unroll
        for (int j = 0; j < 8; ++j) {
          int d = d0 + j;
          ushort2 pr;
          pr.x = (u16)va[j];
          pr.y = (u16)vb[j];
          *(ushort2*)&Vt[d * 64 + (((kvp >> 2) ^ (d & 7)) << 3) + (kvp & 3) * 2] = pr;
        }
      }
      __syncthreads();

      // ---- QK^T: S[16 q x 64 kv] = 4 frags
      f32x4 s[4] = {};
#pragma unroll
      for (int kb = 0; kb < 4; ++kb) {
        int row = kb * 16 + l15;
        short8 k0f = *(const short8*)&Ks[row * 64 + ((g ^ (row & 7)) << 3)];
        short8 k1f = *(const short8*)&Ks[row * 64 + (((4 + g) ^ (row & 7)) << 3)];
        s[kb] = mfma16(qf0, k0f, s[kb]);
        s[kb] = mfma16(qf1, k1f, s[kb]);
      }
      if (t == c) {  // diagonal tile: causal mask
#pragma unroll
        for (int kb = 0; kb < 4; ++kb) {
          int kvcol = kv0 + kb * 16 + l15;
#pragma unroll
          for (int r = 0; r < 4; ++r)
            if (kvcol > qr0 + g * 4 + r) s[kb][r] = -1.0e30f;
        }
      }
      // ---- online softmax (row reduce across 16-lane groups)
#pragma unroll
      for (int r = 0; r < 4; ++r) {
        float mx = fmaxf(fmaxf(s[0][r], s[1][r]), fmaxf(s[2][r], s[3][r]));
        mx = fmaxf(mx, __shfl_xor(mx, 1));
        mx = fmaxf(mx, __shfl_xor(mx, 2));
        mx = fmaxf(mx, __shfl_xor(mx, 4));
        mx = fmaxf(mx, __shfl_xor(mx, 8));
        float nm = fmaxf(m_[r], mx);
        float sc = __expf(m_[r] - nm);
        float p0 = __expf(s[0][r] - nm);
        float p1 = __expf(s[1][r] - nm);
        float p2 = __expf(s[2][r] - nm);
        float p3 = __expf(s[3][r] - nm);
        float rs = (p0 + p1) + (p2 + p3);
        rs += __shfl_xor(rs, 1);
        rs += __shfl_xor(rs, 2);
        rs += __shfl_xor(rs, 4);
        rs += __shfl_xor(rs, 8);
        l_[r] = l_[r] * sc + rs;
        m_[r] = nm;
        o[0][r] *= sc; o[1][r] *= sc; o[2][r] *= sc; o[3][r] *= sc;
        int rowP = g * 4 + r, rx = rowP & 7;
        u16* pw = &Ps[w][rowP * 64];
        int sub = l15 & 7, hi = l15 >> 3;
        pw[(((hi)     ^ rx) << 3) | sub] = f2b(p0);
        pw[(((2 + hi) ^ rx) << 3) | sub] = f2b(p1);
        pw[(((4 + hi) ^ rx) << 3) | sub] = f2b(p2);
        pw[(((6 + hi) ^ rx) << 3) | sub] = f2b(p3);
      }
      // ---- PV: O[16x64] += P[16x64] * V[64x64]
      short8 pf0 = *(const short8*)&Ps[w][l15 * 64 + ((g ^ (l15 & 7)) << 3)];
      short8 pf1 = *(const short8*)&Ps[w][l15 * 64 + (((4 + g) ^ (l15 & 7)) << 3)];
#pragma unroll
      for (int nb = 0; nb < 4; ++nb) {
        int rv = nb * 16 + l15;
        short8 v0f = *(const short8*)&Vt[rv * 64 + ((g ^ (rv & 7)) << 3)];
        short8 v1f = *(const short8*)&Vt[rv * 64 + (((4 + g) ^ (rv & 7)) << 3)];
        o[nb] = mfma16(pf0, v0f, o[nb]);
        o[nb] = mfma16(pf1, v1f, o[nb]);
      }
    }

    // epilogue: normalize, write interleaved [s][h*64+d] bf16
    float invl[4];
#pragma unroll
    for (int r = 0; r < 4; ++r) invl[r] = 1.0f / l_[r];
#pragma unroll
    for (int nb = 0; nb < 4; ++nb) {
#pragma unroll
      for (int r = 0; r < 4; ++r) {
        int row = qr0 + g * 4 + r;
        int col = h * HD + nb * 16 + l15;
        Ob[(size_t)row * DIMM + col] = f2b(o[nb][r] * invl[r]);
      }
    }
  }
}

// ---------------- workspace layout (bytes) --------------------------------------
#define OFF_XB 0u
#define OFF_WQKV 8388608u   // wq,wk,wv contiguous: 3072x1024 bf16 = 6MB
#define OFF_WOB 14680064u   // 2MB
#define OFF_QKV 16777216u   // fp32 [4096][3072] = 48MB
#define OFF_QH 67108864u
#define OFF_KH 75497472u
#define OFF_VH 83886080u
#define OFF_OB 92274688u
// end: 100663296 (96 MB)

extern "C" void kernel_launch(void* const* d_in, const int* in_sizes, int n_in,
                              void* d_out, int out_size, void* d_ws, size_t ws_size,
                              hipStream_t stream) {
  const float* x = (const float*)d_in[0];
  const float* Wq = (const float*)d_in[1];
  const float* Wk = (const float*)d_in[2];
  const float* Wv = (const float*)d_in[3];
  const float* Wo = (const float*)d_in[4];
  float* out = (float*)d_out;
  char* ws = (char*)d_ws;

  u16* xb = (u16*)(ws + OFF_XB);
  u16* wqkv = (u16*)(ws + OFF_WQKV);
  u16* wqb = wqkv;
  u16* wkb = wqkv + (size_t)DIMM * DIMM;
  u16* wvb = wqkv + (size_t)2 * DIMM * DIMM;
  u16* wob = (u16*)(ws + OFF_WOB);
  float* qkv = (float*)(ws + OFF_QKV);
  u16* Qh = (u16*)(ws + OFF_QH);
  u16* Kh = (u16*)(ws + OFF_KH);
  u16* Vh = (u16*)(ws + OFF_VH);
  u16* Ob = (u16*)(ws + OFF_OB);

  cvt_all<<<8192, 256, 0, stream>>>(x, Wq, Wk, Wv, Wo, xb, wqb, wkb, wvb, wob);

  // fused QKV projection: [4096,1024] x [3072,1024]^T -> qkv [4096][3072]
  gemm_bt<<<dim3(SEQ / 128, 3072 / 128), 256, 0, stream>>>(xb, wqkv, qkv, DIMM, 3072);

  rope_cvt<<<(SEQ * 32) / 256, 256, 0, stream>>>(qkv, Qh, Kh, Vh);

  attn_fwd<<<dim3(32, NH), 256, 0, stream>>>(Qh, Kh, Vh, Ob);

  gemm_bt<<<dim3(SEQ / 128, DIMM / 128), 256, 0, stream>>>(Ob, wob, out, DIMM, DIMM);
}

// Round 3
// 256.716 us; speedup vs baseline: 2.1941x; 1.2508x over previous
//
#include <hip/hip_runtime.h>

// MHA forward: x[4096,1024] fp32, W{q,k,v,o}[1024,1024] fp32 -> out[4096,1024] fp32
// cvt->bf16 | fused QKV gemm | RoPE | flash attn (swapped-QK^T, in-reg softmax,
// XCD-pinned balanced schedule) | O-proj gemm

typedef __attribute__((ext_vector_type(4))) float f32x4;
typedef __attribute__((ext_vector_type(8))) short short8;
typedef __attribute__((ext_vector_type(2))) unsigned int u32x2;
typedef unsigned short u16;

#define SEQ 4096
#define DIMM 1024
#define NH 16
#define HD 64

__device__ __forceinline__ u16 f2b(float f) {
  unsigned u = __float_as_uint(f);
  u += 0x7FFFu + ((u >> 16) & 1u);
  return (u16)(u >> 16);
}
__device__ __forceinline__ float b2f(unsigned v) {
  return __uint_as_float(v << 16);
}
__device__ __forceinline__ f32x4 mfma16(short8 a, short8 b, f32x4 c) {
  return __builtin_amdgcn_mfma_f32_16x16x32_bf16(a, b, c, 0, 0, 0);
}
#define GLL16(gp, lp)                                                        \
  __builtin_amdgcn_global_load_lds(                                          \
      (const __attribute__((address_space(1))) unsigned int*)(gp),           \
      (__attribute__((address_space(3))) unsigned int*)(lp), 16, 0, 0)

// ---------------- convert x + 4 weights to bf16 ---------------------------------
__global__ __launch_bounds__(256) void cvt_all(
    const float* __restrict__ x, const float* __restrict__ wq,
    const float* __restrict__ wk, const float* __restrict__ wv,
    const float* __restrict__ wo,
    u16* __restrict__ xb, u16* __restrict__ wqb, u16* __restrict__ wkb,
    u16* __restrict__ wvb, u16* __restrict__ wob) {
  int i = blockIdx.x * 256 + threadIdx.x;
  const float* src;
  u16* dst;
  int j;
  if (i < 1048576) {
    src = x; dst = xb; j = i;
  } else {
    int t = i - 1048576;
    int wsel = t >> 18;
    j = t & 262143;
    src = (wsel == 0) ? wq : (wsel == 1) ? wk : (wsel == 2) ? wv : wo;
    dst = (wsel == 0) ? wqb : (wsel == 1) ? wkb : (wsel == 2) ? wvb : wob;
  }
  float4 v = ((const float4*)src)[j];
  ushort4 o;
  o.x = f2b(v.x); o.y = f2b(v.y); o.z = f2b(v.z); o.w = f2b(v.w);
  ((ushort4*)dst)[j] = o;
}

// ---------------- GEMM: C[M,N] = A[M,K] * B[N,K]^T ------------------------------
template <int BF16OUT>
__global__ __launch_bounds__(256) void gemm_bt(
    const u16* __restrict__ A, const u16* __restrict__ B, void* __restrict__ Cv,
    int K, int N) {
  __shared__ __align__(16) u16 As[128 * 32];
  __shared__ __align__(16) u16 Bs[128 * 32];
  const int tid = threadIdx.x;
  const int bm = blockIdx.x, bn = blockIdx.y;
  const int w = tid >> 6, lane = tid & 63;
  const int wm = w >> 1, wn = w & 1;
  const int l15 = lane & 15, g = lane >> 4;

  f32x4 acc[4][4] = {};

  const u16* Ap0 = A + (size_t)(bm * 128 + (tid >> 2)) * K + (tid & 3) * 8;
  const u16* Ap1 = Ap0 + (size_t)64 * K;
  const u16* Bp0 = B + (size_t)(bn * 128 + (tid >> 2)) * K + (tid & 3) * 8;
  const u16* Bp1 = Bp0 + (size_t)64 * K;
  u16* ldsA0 = &As[w * 512];
  u16* ldsA1 = &As[2048 + w * 512];
  u16* ldsB0 = &Bs[w * 512];
  u16* ldsB1 = &Bs[2048 + w * 512];

  for (int k0 = 0; k0 < K; k0 += 32) {
    __syncthreads();
    GLL16(Ap0 + k0, ldsA0);
    GLL16(Ap1 + k0, ldsA1);
    GLL16(Bp0 + k0, ldsB0);
    GLL16(Bp1 + k0, ldsB1);
    __syncthreads();
    short8 af[4], bf[4];
#pragma unroll
    for (int m = 0; m < 4; ++m)
      af[m] = *(const short8*)&As[(wm * 64 + m * 16 + l15) * 32 + g * 8];
#pragma unroll
    for (int n = 0; n < 4; ++n)
      bf[n] = *(const short8*)&Bs[(wn * 64 + n * 16 + l15) * 32 + g * 8];
#pragma unroll
    for (int m = 0; m < 4; ++m)
#pragma unroll
      for (int n = 0; n < 4; ++n)
        acc[m][n] = mfma16(af[m], bf[n], acc[m][n]);
  }

#pragma unroll
  for (int m = 0; m < 4; ++m) {
    int grow = bm * 128 + wm * 64 + m * 16 + g * 4;
#pragma unroll
    for (int n = 0; n < 4; ++n) {
      int gcol = bn * 128 + wn * 64 + n * 16 + l15;
#pragma unroll
      for (int r = 0; r < 4; ++r) {
        if (BF16OUT)
          ((u16*)Cv)[(size_t)(grow + r) * N + gcol] = f2b(acc[m][n][r]);
        else
          ((float*)Cv)[(size_t)(grow + r) * N + gcol] = acc[m][n][r];
      }
    }
  }
}

// ---------------- RoPE + head-major relayout (bf16 in) --------------------------
__global__ __launch_bounds__(256) void rope_cvt(
    const u16* __restrict__ qkvb, u16* __restrict__ Qh, u16* __restrict__ Kh,
    u16* __restrict__ Vh) {
  int gid = blockIdx.x * 256 + threadIdx.x;  // 4096*32
  int s = gid >> 5, i = gid & 31;
  float inv = powf(10000.0f, -(float)i * (1.0f / 32.0f));
  float ang = (float)s * inv;
  float sv, cv;
  sincosf(ang, &sv, &cv);
#pragma unroll
  for (int h = 0; h < NH; ++h) {
    size_t base = (size_t)s * 3072 + h * HD + 2 * i;
    unsigned q2 = *(const unsigned*)(qkvb + base);
    unsigned k2 = *(const unsigned*)(qkvb + base + 1024);
    unsigned v2 = *(const unsigned*)(qkvb + base + 2048);
    float qx = b2f(q2 & 0xffffu), qy = b2f(q2 >> 16);
    float kx = b2f(k2 & 0xffffu), ky = b2f(k2 >> 16);
    size_t ob = ((size_t)h * SEQ + s) * HD + 2 * i;
    ushort2 t;
    t.x = f2b((qx * cv - qy * sv) * 0.125f);
    t.y = f2b((qy * cv + qx * sv) * 0.125f);
    *(ushort2*)(Qh + ob) = t;
    t.x = f2b(kx * cv - ky * sv);
    t.y = f2b(ky * cv + kx * sv);
    *(ushort2*)(Kh + ob) = t;
    *(unsigned*)(Vh + ob) = v2;
  }
}

// ---------------- causal flash attention ----------------------------------------
// 512 blocks (1D); L&7 = xcd hosts heads {xcd, xcd+8}; slot order pairs heavy+light
// chunks on a CU (68 tiles each). Block = 4 waves x 32 q-rows = 128-q chunk, KVBLK=64.
// Swapped QK^T: S^T = mfma(K, Q) -> per-lane row-local softmax state.
__global__ __launch_bounds__(256) void attn_fwd(
    const u16* __restrict__ Qh, const u16* __restrict__ Kh,
    const u16* __restrict__ Vh, u16* __restrict__ Ob) {
  __shared__ __align__(16) u16 Ks[64 * 64];      // [kv][d], chunk^=(row&7)
  __shared__ __align__(16) u16 Vt[64 * 64];      // [d][kv], chunk^=((d^(d>>3))&7)
  __shared__ __align__(16) u16 Ps[4][32 * 64];   // per-wave [q][kv], chunk^=(row&7)

  const int L = blockIdx.x;
  const int xcd = L & 7, sl = L >> 3;
  const int h = xcd + ((sl >> 5) << 3);
  const int c = (sl < 32) ? (31 - sl) : (sl - 32);

  const int tid = threadIdx.x, w = tid >> 6, lane = tid & 63;
  const int l15 = lane & 15, g = lane >> 4;
  const int qr0w = c * 128 + w * 32;
  const size_t hS = (size_t)h * SEQ;

  // K staging geometry (GLL, pre-swizzled source)
  const int krow0 = w * 8 + (lane >> 3);
  const int kc0 = ((lane & 7) ^ (krow0 & 7)) * 8;
  const int krow1 = 32 + krow0;
  const int kc1 = ((lane & 7) ^ (krow1 & 7)) * 8;
  const int kvp = tid >> 3, d0 = (tid & 7) * 8;  // V transpose staging

  short8 qf[2][2];
#pragma unroll
  for (int qb = 0; qb < 2; ++qb) {
    const u16* Qp = Qh + (hS + qr0w + qb * 16 + l15) * HD + g * 8;
    qf[qb][0] = *(const short8*)(Qp);
    qf[qb][1] = *(const short8*)(Qp + 32);
  }

  f32x4 o[2][4] = {};
  float m_[2] = {-3.0e38f, -3.0e38f};
  float lg[2] = {0.f, 0.f};

  const int T = 2 * c + 2;
  const int t_end = 2 * c + (w >= 2 ? 1 : 0);

  for (int t = 0; t < T; ++t) {
    const int kv0 = t * 64;
    __syncthreads();
    GLL16(Kh + (hS + kv0 + krow0) * HD + kc0, &Ks[w * 512]);
    GLL16(Kh + (hS + kv0 + krow1) * HD + kc1, &Ks[2048 + w * 512]);
    {
      const u16* vp = Vh + (hS + kv0 + kvp * 2) * HD + d0;
      short8 va = *(const short8*)vp;
      short8 vb = *(const short8*)(vp + HD);
#pragma unroll
      for (int j = 0; j < 8; ++j) {
        int d = d0 + j;
        int sw = (d ^ (d >> 3)) & 7;
        ushort2 pr;
        pr.x = (u16)va[j];
        pr.y = (u16)vb[j];
        *(ushort2*)&Vt[d * 64 + (((kvp >> 2) ^ sw) << 3) + (kvp & 3) * 2] = pr;
      }
    }
    __syncthreads();
    if (t > t_end) continue;

    // ---- swapped QK^T: S^T[kv][q]; lane: q = qb*16+l15, kv = kb*16+g*4+r
    f32x4 s[2][4] = {};
#pragma unroll
    for (int kb = 0; kb < 4; ++kb) {
      int row = kb * 16 + l15;
      short8 k0 = *(const short8*)&Ks[row * 64 + ((g ^ (row & 7)) << 3)];
      short8 k1 = *(const short8*)&Ks[row * 64 + (((4 + g) ^ (row & 7)) << 3)];
#pragma unroll
      for (int qb = 0; qb < 2; ++qb) {
        s[qb][kb] = mfma16(k0, qf[qb][0], s[qb][kb]);
        s[qb][kb] = mfma16(k1, qf[qb][1], s[qb][kb]);
      }
    }
    if (t == t_end) {  // causal mask
#pragma unroll
      for (int qb = 0; qb < 2; ++qb) {
        int q = qr0w + qb * 16 + l15;
#pragma unroll
        for (int kb = 0; kb < 4; ++kb) {
          int kvb = kv0 + kb * 16 + g * 4;
#pragma unroll
          for (int r = 0; r < 4; ++r)
            if (kvb + r > q) s[qb][kb][r] = -1.0e30f;
        }
      }
    }

    // ---- in-register online softmax
    float mx[2];
#pragma unroll
    for (int qb = 0; qb < 2; ++qb) {
      float a0 = fmaxf(fmaxf(s[qb][0][0], s[qb][0][1]), fmaxf(s[qb][0][2], s[qb][0][3]));
      float a1 = fmaxf(fmaxf(s[qb][1][0], s[qb][1][1]), fmaxf(s[qb][1][2], s[qb][1][3]));
      float a2 = fmaxf(fmaxf(s[qb][2][0], s[qb][2][1]), fmaxf(s[qb][2][2], s[qb][2][3]));
      float a3 = fmaxf(fmaxf(s[qb][3][0], s[qb][3][1]), fmaxf(s[qb][3][2], s[qb][3][3]));
      float m0 = fmaxf(fmaxf(a0, a1), fmaxf(a2, a3));
      m0 = fmaxf(m0, __shfl_xor(m0, 16));
      m0 = fmaxf(m0, __shfl_xor(m0, 32));
      mx[qb] = m0;
    }
    int defer = __all((mx[0] - m_[0] <= 8.0f) && (mx[1] - m_[1] <= 8.0f));
    if (!defer) {
#pragma unroll
      for (int qb = 0; qb < 2; ++qb) {
        float nm = fmaxf(m_[qb], mx[qb]);
        float sc = __expf(m_[qb] - nm);
        m_[qb] = nm;
        lg[qb] *= sc;
#pragma unroll
        for (int r = 0; r < 4; ++r) {
          float so = __shfl(sc, g * 4 + r);
          o[qb][0][r] *= so;
          o[qb][1][r] *= so;
          o[qb][2][r] *= so;
          o[qb][3][r] *= so;
        }
      }
    }
    // ---- P = exp(S - m), pack to bf16, store per-wave LDS tile
#pragma unroll
    for (int qb = 0; qb < 2; ++qb) {
      int row = qb * 16 + l15;
      float ps = 0.f;
#pragma unroll
      for (int kb = 0; kb < 4; ++kb) {
        float p0 = __expf(s[qb][kb][0] - m_[qb]);
        float p1 = __expf(s[qb][kb][1] - m_[qb]);
        float p2 = __expf(s[qb][kb][2] - m_[qb]);
        float p3 = __expf(s[qb][kb][3] - m_[qb]);
        ps += (p0 + p1) + (p2 + p3);
        unsigned w0, w1;
        asm("v_cvt_pk_bf16_f32 %0, %1, %2" : "=v"(w0) : "v"(p0), "v"(p1));
        asm("v_cvt_pk_bf16_f32 %0, %1, %2" : "=v"(w1) : "v"(p2), "v"(p3));
        int ch = (kb * 2 + (g >> 1)) ^ (row & 7);
        *(u32x2*)&Ps[w][row * 64 + ch * 8 + (g & 1) * 4] = (u32x2){w0, w1};
      }
      lg[qb] += ps;
    }
    // ---- PV: O[32q][64d] += P * V
    short8 vf[4][2];
#pragma unroll
    for (int nb = 0; nb < 4; ++nb) {
      int rv = nb * 16 + l15;
      int swv = (rv ^ (rv >> 3)) & 7;
      vf[nb][0] = *(const short8*)&Vt[rv * 64 + ((g ^ swv) << 3)];
      vf[nb][1] = *(const short8*)&Vt[rv * 64 + (((4 + g) ^ swv) << 3)];
    }
#pragma unroll
    for (int qb = 0; qb < 2; ++qb) {
      int row = qb * 16 + l15;
      short8 pa0 = *(const short8*)&Ps[w][row * 64 + ((g ^ (row & 7)) << 3)];
      short8 pa1 = *(const short8*)&Ps[w][row * 64 + (((4 + g) ^ (row & 7)) << 3)];
#pragma unroll
      for (int nb = 0; nb < 4; ++nb) {
        o[qb][nb] = mfma16(pa0, vf[nb][0], o[qb][nb]);
        o[qb][nb] = mfma16(pa1, vf[nb][1], o[qb][nb]);
      }
    }
  }

  // epilogue
#pragma unroll
  for (int qb = 0; qb < 2; ++qb) {
    float l = lg[qb];
    l += __shfl_xor(l, 16);
    l += __shfl_xor(l, 32);
    float il = 1.0f / l;
#pragma unroll
    for (int r = 0; r < 4; ++r) {
      float ilr = __shfl(il, g * 4 + r);
      int qrow = qr0w + qb * 16 + g * 4 + r;
#pragma unroll
      for (int nb = 0; nb < 4; ++nb)
        Ob[(size_t)qrow * DIMM + h * HD + nb * 16 + l15] = f2b(o[qb][nb][r] * ilr);
    }
  }
}

// ---------------- workspace layout (bytes) --------------------------------------
#define OFF_XB 0u
#define OFF_WQKV 8388608u    // 3072x1024 bf16 = 6MB
#define OFF_WOB 14680064u    // 2MB
#define OFF_QKVB 16777216u   // bf16 [4096][3072] = 24MB
#define OFF_QH 41943040u
#define OFF_KH 50331648u
#define OFF_VH 58720256u
#define OFF_OB 67108864u
// end: 75497472 (72 MB)

extern "C" void kernel_launch(void* const* d_in, const int* in_sizes, int n_in,
                              void* d_out, int out_size, void* d_ws, size_t ws_size,
                              hipStream_t stream) {
  const float* x = (const float*)d_in[0];
  const float* Wq = (const float*)d_in[1];
  const float* Wk = (const float*)d_in[2];
  const float* Wv = (const float*)d_in[3];
  const float* Wo = (const float*)d_in[4];
  float* out = (float*)d_out;
  char* ws = (char*)d_ws;

  u16* xb = (u16*)(ws + OFF_XB);
  u16* wqkv = (u16*)(ws + OFF_WQKV);
  u16* wqb = wqkv;
  u16* wkb = wqkv + (size_t)DIMM * DIMM;
  u16* wvb = wqkv + (size_t)2 * DIMM * DIMM;
  u16* wob = (u16*)(ws + OFF_WOB);
  u16* qkvb = (u16*)(ws + OFF_QKVB);
  u16* Qh = (u16*)(ws + OFF_QH);
  u16* Kh = (u16*)(ws + OFF_KH);
  u16* Vh = (u16*)(ws + OFF_VH);
  u16* Ob = (u16*)(ws + OFF_OB);

  cvt_all<<<8192, 256, 0, stream>>>(x, Wq, Wk, Wv, Wo, xb, wqb, wkb, wvb, wob);

  gemm_bt<1><<<dim3(SEQ / 128, 3072 / 128), 256, 0, stream>>>(xb, wqkv, qkvb, DIMM, 3072);

  rope_cvt<<<(SEQ * 32) / 256, 256, 0, stream>>>(qkvb, Qh, Kh, Vh);

  attn_fwd<<<512, 256, 0, stream>>>(Qh, Kh, Vh, Ob);

  gemm_bt<0><<<dim3(SEQ / 128, DIMM / 128), 256, 0, stream>>>(Ob, wob, out, DIMM, DIMM);
}